// Round 1
// baseline (88.031 us; speedup 1.0000x reference)
//
#include <hip/hip_runtime.h>
#include <hip/hip_bf16.h>

// MaskNet edge scorer:
//   y1[n] = W1[:, :128] @ x[n] + b1   (64 dims, bf16, folded bias)
//   y2[n] = W1[:, 128:] @ x[n]        (64 dims, bf16)
//   s[e]  = sigmoid( w2 . relu(y1[row] + y2[col]) + b2 )
// Table ytab: [N][128] bf16, dims 0..63 = y1, 64..127 = y2. 12.8 MB in d_ws.

typedef __attribute__((ext_vector_type(8))) short bf16x8;
typedef __attribute__((ext_vector_type(4))) float f32x4;

#define IN_DIM 128
#define HIDDEN 64

// round-to-nearest-even f32 -> bf16 (bit trick, matches HW RN)
__device__ __forceinline__ short f2bf(float f) {
    union { float f; unsigned u; } v; v.f = f;
    unsigned r = v.u + 0x7FFFu + ((v.u >> 16) & 1u);
    return (short)(r >> 16);
}

__device__ __forceinline__ bf16x8 pack8(const float4& lo, const float4& hi) {
    bf16x8 b;
    b[0] = f2bf(lo.x); b[1] = f2bf(lo.y); b[2] = f2bf(lo.z); b[3] = f2bf(lo.w);
    b[4] = f2bf(hi.x); b[5] = f2bf(hi.y); b[6] = f2bf(hi.z); b[7] = f2bf(hi.w);
    return b;
}

// ---------------- node projection: one wave per 16-node tile ----------------
// y[n][d] = sum_k x[n][k] * Wp[d][k], Wp[d] = w1[d][:128] (d<64) else w1[d-64][128:]
// MFMA 16x16x32 bf16: A[m][k] lane: m=l&15, k=8*(l>>4)+i ; B[k][n]: n=l&15, same k.
// D: col=l&15 (dim), row=(l>>4)*4+r (node).
__global__ __launch_bounds__(256) void node_proj_kernel(
    const float* __restrict__ x,    // [N][128]
    const float* __restrict__ w1,   // [64][256]
    const float* __restrict__ b1,   // [64]
    __hip_bfloat16* __restrict__ ytab, // [N][128]
    int N, int ntiles)
{
    int wave = (int)((blockIdx.x * blockDim.x + threadIdx.x) >> 6);
    if (wave >= ntiles) return;
    int lane = threadIdx.x & 63;
    int m = lane & 15;       // A row / D col index
    int g = lane >> 4;       // k-group / D row group
    int n0 = wave * 16;

    int node = n0 + m; if (node >= N) node = N - 1;
    const float* xr = x + (size_t)node * IN_DIM;

    bf16x8 afrag[4];
#pragma unroll
    for (int kk = 0; kk < 4; ++kk) {
        int k0 = kk * 32 + g * 8;
        float4 lo = *(const float4*)(xr + k0);
        float4 hi = *(const float4*)(xr + k0 + 4);
        afrag[kk] = pack8(lo, hi);
    }

    f32x4 acc[8] = {};
#pragma unroll
    for (int dt = 0; dt < 8; ++dt) {
        int o = dt * 16 + m;               // output dim this lane supplies for B
        const float* wr;
        int kbase;
        if (o < HIDDEN) { wr = w1 + (size_t)o * (2 * IN_DIM);            kbase = 0; }
        else            { wr = w1 + (size_t)(o - HIDDEN) * (2 * IN_DIM); kbase = IN_DIM; }
#pragma unroll
        for (int kk = 0; kk < 4; ++kk) {
            int k0 = kbase + kk * 32 + g * 8;
            float4 lo = *(const float4*)(wr + k0);
            float4 hi = *(const float4*)(wr + k0 + 4);
            bf16x8 bfrag = pack8(lo, hi);
            acc[dt] = __builtin_amdgcn_mfma_f32_16x16x32_bf16(afrag[kk], bfrag, acc[dt], 0, 0, 0);
        }
    }

    // epilogue: fold b1 into dims < 64, store bf16
#pragma unroll
    for (int dt = 0; dt < 8; ++dt) {
        int dim = dt * 16 + m;
        float bias = (dim < HIDDEN) ? b1[dim] : 0.f;
#pragma unroll
        for (int r = 0; r < 4; ++r) {
            int nrow = n0 + g * 4 + r;
            if (nrow < N) {
                float v = acc[dt][r] + bias;
                ((unsigned short*)ytab)[(size_t)nrow * IN_DIM + dim] = (unsigned short)f2bf(v);
            }
        }
    }
}

// ---------------- edge kernel: 8 lanes per edge ----------------
__device__ __forceinline__ float dimpair(unsigned u1, unsigned u2, float wlo, float whi, float acc) {
    float a0 = __uint_as_float(u1 << 16);
    float a1 = __uint_as_float(u1 & 0xffff0000u);
    float b0 = __uint_as_float(u2 << 16);
    float b1v = __uint_as_float(u2 & 0xffff0000u);
    float h0 = fmaxf(a0 + b0, 0.f);
    float h1 = fmaxf(a1 + b1v, 0.f);
    acc = fmaf(h0, wlo, acc);
    acc = fmaf(h1, whi, acc);
    return acc;
}

__global__ __launch_bounds__(256) void edge_kernel(
    const int* __restrict__ ei,              // [2][E] int32
    const __hip_bfloat16* __restrict__ ytab, // [N][128]
    const float* __restrict__ w2,            // [64]
    const float* __restrict__ b2,            // [1]
    float* __restrict__ out,                 // [E]
    int E)
{
    int t = (int)(blockIdx.x * 256 + threadIdx.x);
    int e = t >> 3;
    if (e >= E) return;
    int sub = t & 7;

    int row = ei[e];
    int col = ei[E + e];

    const uint4* p1 = (const uint4*)((const unsigned short*)ytab + (size_t)row * IN_DIM) + sub;
    const uint4* p2 = (const uint4*)((const unsigned short*)ytab + (size_t)col * IN_DIM + HIDDEN) + sub;
    uint4 ua = *p1;   // 8 bf16 of y1[row], dims sub*8..sub*8+7
    uint4 ub = *p2;   // 8 bf16 of y2[col]

    float4 w2a = *((const float4*)(w2) + sub * 2);
    float4 w2b = *((const float4*)(w2) + sub * 2 + 1);

    float acc = 0.f;
    acc = dimpair(ua.x, ub.x, w2a.x, w2a.y, acc);
    acc = dimpair(ua.y, ub.y, w2a.z, w2a.w, acc);
    acc = dimpair(ua.z, ub.z, w2b.x, w2b.y, acc);
    acc = dimpair(ua.w, ub.w, w2b.z, w2b.w, acc);

    acc += __shfl_xor(acc, 1);
    acc += __shfl_xor(acc, 2);
    acc += __shfl_xor(acc, 4);

    if (sub == 0) {
        float z = acc + b2[0];
        out[e] = 1.f / (1.f + __expf(-z));
    }
}

extern "C" void kernel_launch(void* const* d_in, const int* in_sizes, int n_in,
                              void* d_out, int out_size, void* d_ws, size_t ws_size,
                              hipStream_t stream) {
    const float* x  = (const float*)d_in[0];
    const int*   ei = (const int*)d_in[1];
    const float* w1 = (const float*)d_in[2];
    const float* b1 = (const float*)d_in[3];
    const float* w2 = (const float*)d_in[4];
    const float* b2 = (const float*)d_in[5];
    float* out = (float*)d_out;

    int N = in_sizes[0] / IN_DIM;
    int E = in_sizes[1] / 2;

    __hip_bfloat16* ytab = (__hip_bfloat16*)d_ws;  // [N][128] bf16 = 12.8 MB

    int ntiles = (N + 15) / 16;
    int nblocks = (ntiles + 3) / 4;                 // 4 waves (tiles) per 256-thr block
    node_proj_kernel<<<nblocks, 256, 0, stream>>>(x, w1, b1, ytab, N, ntiles);

    long long tthreads = (long long)E * 8;
    int eblocks = (int)((tthreads + 255) / 256);
    edge_kernel<<<eblocks, 256, 0, stream>>>(ei, ytab, w2, b2, out, E);
}

// Round 2
// 66.953 us; speedup vs baseline: 1.3148x; 1.3148x over previous
//
#include <hip/hip_runtime.h>
#include <hip/hip_bf16.h>

// MaskNet edge scorer:
//   y1[n] = W1[:, :128] @ x[n] + b1   (64 dims, bf16, folded bias)
//   y2[n] = W1[:, 128:] @ x[n]        (64 dims, bf16)
//   s[e]  = sigmoid( w2 . relu(y1[row] + y2[col]) + b2 )
// Table ytab: [N][128] bf16, dims 0..63 = y1, 64..127 = y2. 12.8 MB in d_ws.

typedef __attribute__((ext_vector_type(8))) short bf16x8;
typedef __attribute__((ext_vector_type(4))) float f32x4;

#define IN_DIM 128
#define HIDDEN 64

// round-to-nearest-even f32 -> bf16 (bit trick, matches HW RN)
__device__ __forceinline__ short f2bf(float f) {
    union { float f; unsigned u; } v; v.f = f;
    unsigned r = v.u + 0x7FFFu + ((v.u >> 16) & 1u);
    return (short)(r >> 16);
}

__device__ __forceinline__ bf16x8 pack8(const float4& lo, const float4& hi) {
    bf16x8 b;
    b[0] = f2bf(lo.x); b[1] = f2bf(lo.y); b[2] = f2bf(lo.z); b[3] = f2bf(lo.w);
    b[4] = f2bf(hi.x); b[5] = f2bf(hi.y); b[6] = f2bf(hi.z); b[7] = f2bf(hi.w);
    return b;
}

// ---------------- node projection ----------------
// One wave per 16-node tile; per block, w1 is converted ONCE into a 32 KB LDS
// fragment table (coalesced), then all waves read B-fragments via ds_read_b128.
// MFMA 16x16x32 bf16: A[m][k] lane: m=l&15, k=8*(l>>4)+i ; B[k][n]: n=l&15.
// D: col=l&15 (dim), row=(l>>4)*4+r (node).
__global__ __launch_bounds__(256) void node_proj_kernel(
    const float* __restrict__ x,    // [N][128]
    const float* __restrict__ w1,   // [64][256]
    const float* __restrict__ b1,   // [64]
    unsigned short* __restrict__ ytab, // [N][128] bf16 bits
    int N, int ntiles)
{
    __shared__ short wfrag[2048 * 8];   // 32 KB: [dt*4+kk][lane][8]

    // Cooperative w1 -> LDS fragment conversion. Thread v handles w1 flat
    // floats [v*64, v*64+64) — contiguous 256 B global reads per thread.
    {
        int v = threadIdx.x;
#pragma unroll
        for (int j = 0; j < 8; ++j) {
            int f = v * 64 + j * 8;          // flat index into w1 (64*256)
            int r = f >> 8;                  // w1 row (0..63)
            int k = f & 255;                 // col in [0,256)
            float4 lo = *(const float4*)(w1 + f);
            float4 hi = *(const float4*)(w1 + f + 4);
            int o, kk, g;
            if (k < IN_DIM) { o = r;          kk = k >> 5;             g = (k & 31) >> 3; }
            else            { o = r + HIDDEN; kk = (k - IN_DIM) >> 5;  g = ((k - IN_DIM) & 31) >> 3; }
            int dt = o >> 4, m = o & 15;
            int lane = g * 16 + m;
            *(bf16x8*)&wfrag[((dt * 4 + kk) * 64 + lane) * 8] = pack8(lo, hi);
        }
    }
    __syncthreads();

    int wave = (int)((blockIdx.x * blockDim.x + threadIdx.x) >> 6);
    if (wave < ntiles) {
        int lane = threadIdx.x & 63;
        int m = lane & 15;       // A row / D col index
        int g = lane >> 4;       // k-group / D row group
        int n0 = wave * 16;

        int node = n0 + m; if (node >= N) node = N - 1;
        const float* xr = x + (size_t)node * IN_DIM;

        bf16x8 afrag[4];
#pragma unroll
        for (int kk = 0; kk < 4; ++kk) {
            int k0 = kk * 32 + g * 8;
            float4 lo = *(const float4*)(xr + k0);
            float4 hi = *(const float4*)(xr + k0 + 4);
            afrag[kk] = pack8(lo, hi);
        }

        f32x4 acc[8] = {};
#pragma unroll
        for (int dt = 0; dt < 8; ++dt) {
#pragma unroll
            for (int kk = 0; kk < 4; ++kk) {
                bf16x8 bfrag = *(const bf16x8*)&wfrag[((dt * 4 + kk) * 64 + lane) * 8];
                acc[dt] = __builtin_amdgcn_mfma_f32_16x16x32_bf16(afrag[kk], bfrag, acc[dt], 0, 0, 0);
            }
        }

        // epilogue: fold b1 into dims < 64, store bf16
#pragma unroll
        for (int dt = 0; dt < 8; ++dt) {
            int dim = dt * 16 + m;
            float bias = (dim < HIDDEN) ? b1[dim] : 0.f;
#pragma unroll
            for (int r = 0; r < 4; ++r) {
                int nrow = n0 + g * 4 + r;
                if (nrow < N) {
                    float v = acc[dt][r] + bias;
                    ytab[(size_t)nrow * IN_DIM + dim] = (unsigned short)f2bf(v);
                }
            }
        }
    }
}

// ---------------- edge kernel: 8 lanes per edge, 4 edges per group ----------------
__device__ __forceinline__ float dimpair(unsigned u1, unsigned u2, float wlo, float whi, float acc) {
    float a0 = __uint_as_float(u1 << 16);
    float a1 = __uint_as_float(u1 & 0xffff0000u);
    float b0 = __uint_as_float(u2 << 16);
    float b1v = __uint_as_float(u2 & 0xffff0000u);
    float h0 = fmaxf(a0 + b0, 0.f);
    float h1 = fmaxf(a1 + b1v, 0.f);
    acc = fmaf(h0, wlo, acc);
    acc = fmaf(h1, whi, acc);
    return acc;
}

__device__ __forceinline__ float edge_dot(const uint4& ua, const uint4& ub,
                                          const float4& w2a, const float4& w2b) {
    float acc = 0.f;
    acc = dimpair(ua.x, ub.x, w2a.x, w2a.y, acc);
    acc = dimpair(ua.y, ub.y, w2a.z, w2a.w, acc);
    acc = dimpair(ua.z, ub.z, w2b.x, w2b.y, acc);
    acc = dimpair(ua.w, ub.w, w2b.z, w2b.w, acc);
    acc += __shfl_xor(acc, 1);
    acc += __shfl_xor(acc, 2);
    acc += __shfl_xor(acc, 4);
    return acc;
}

__device__ __forceinline__ float sigmoidf(float z) {
    return 1.f / (1.f + __expf(-z));
}

__global__ __launch_bounds__(256) void edge_kernel(
    const int* __restrict__ ei,                 // [2][E] int32
    const unsigned short* __restrict__ ytab,    // [N][128] bf16 bits
    const float* __restrict__ w2,               // [64]
    const float* __restrict__ b2,               // [1]
    float* __restrict__ out,                    // [E]
    int E)
{
    int t = (int)(blockIdx.x * 256 + threadIdx.x);
    int q = t >> 3;          // edge-quad id
    int sub = t & 7;
    int e0 = q * 4;
    if (e0 >= E) return;

    const char* yb = (const char*)ytab;
    float4 w2a = *((const float4*)w2 + sub * 2);
    float4 w2b = *((const float4*)w2 + sub * 2 + 1);
    int so = sub << 4;

    if (e0 + 4 <= E) {
        int4 rows = *(const int4*)(ei + e0);
        int4 cols = *(const int4*)(ei + E + e0);
        // issue all 8 gathers before any use (latency overlap)
        uint4 a0 = *(const uint4*)(yb + ((rows.x << 8) + so));
        uint4 a1 = *(const uint4*)(yb + ((rows.y << 8) + so));
        uint4 a2 = *(const uint4*)(yb + ((rows.z << 8) + so));
        uint4 a3 = *(const uint4*)(yb + ((rows.w << 8) + so));
        uint4 c0 = *(const uint4*)(yb + ((cols.x << 8) + 128 + so));
        uint4 c1 = *(const uint4*)(yb + ((cols.y << 8) + 128 + so));
        uint4 c2 = *(const uint4*)(yb + ((cols.z << 8) + 128 + so));
        uint4 c3 = *(const uint4*)(yb + ((cols.w << 8) + 128 + so));

        float z0 = edge_dot(a0, c0, w2a, w2b);
        float z1 = edge_dot(a1, c1, w2a, w2b);
        float z2 = edge_dot(a2, c2, w2a, w2b);
        float z3 = edge_dot(a3, c3, w2a, w2b);

        if (sub == 0) {
            float bb = b2[0];
            float4 s;
            s.x = sigmoidf(z0 + bb);
            s.y = sigmoidf(z1 + bb);
            s.z = sigmoidf(z2 + bb);
            s.w = sigmoidf(z3 + bb);
            *(float4*)(out + e0) = s;
        }
    } else {
        float bb = b2[0];
        for (int e = e0; e < E; ++e) {
            int row = ei[e];
            int col = ei[E + e];
            uint4 ua = *(const uint4*)(yb + ((row << 8) + so));
            uint4 ub = *(const uint4*)(yb + ((col << 8) + 128 + so));
            float z = edge_dot(ua, ub, w2a, w2b);
            if (sub == 0) out[e] = sigmoidf(z + bb);
        }
    }
}

extern "C" void kernel_launch(void* const* d_in, const int* in_sizes, int n_in,
                              void* d_out, int out_size, void* d_ws, size_t ws_size,
                              hipStream_t stream) {
    const float* x  = (const float*)d_in[0];
    const int*   ei = (const int*)d_in[1];
    const float* w1 = (const float*)d_in[2];
    const float* b1 = (const float*)d_in[3];
    const float* w2 = (const float*)d_in[4];
    const float* b2 = (const float*)d_in[5];
    float* out = (float*)d_out;

    int N = in_sizes[0] / IN_DIM;
    int E = in_sizes[1] / 2;

    unsigned short* ytab = (unsigned short*)d_ws;  // [N][128] bf16 = 12.8 MB

    int ntiles = (N + 15) / 16;
    int nblocks = (ntiles + 3) / 4;                 // 4 waves (tiles) per 256-thr block
    node_proj_kernel<<<nblocks, 256, 0, stream>>>(x, w1, b1, ytab, N, ntiles);

    long long quads = ((long long)E + 3) / 4;
    long long tthreads = quads * 8;
    int eblocks = (int)((tthreads + 255) / 256);
    edge_kernel<<<eblocks, 256, 0, stream>>>(ei, ytab, w2, b2, out, E);
}

// Round 3
// 65.350 us; speedup vs baseline: 1.3471x; 1.0245x over previous
//
#include <hip/hip_runtime.h>
#include <hip/hip_bf16.h>

// MaskNet edge scorer:
//   y1[n] = W1[:, :128] @ x[n] + b1   (64 dims, bf16, folded bias)
//   y2[n] = W1[:, 128:] @ x[n]        (64 dims, bf16)
//   s[e]  = sigmoid( w2 . relu(y1[row] + y2[col]) + b2 )
// Table ytab: [N][128] bf16, dims 0..63 = y1, 64..127 = y2. 12.8 MB in d_ws.

typedef __attribute__((ext_vector_type(8))) short bf16x8;
typedef __attribute__((ext_vector_type(4))) float f32x4;
typedef __attribute__((ext_vector_type(4))) unsigned short u16x4;

#define IN_DIM 128
#define HIDDEN 64

// round-to-nearest-even f32 -> bf16 (bit trick, matches HW RN)
__device__ __forceinline__ short f2bf(float f) {
    union { float f; unsigned u; } v; v.f = f;
    unsigned r = v.u + 0x7FFFu + ((v.u >> 16) & 1u);
    return (short)(r >> 16);
}

__device__ __forceinline__ bf16x8 pack8(const float4& lo, const float4& hi) {
    bf16x8 b;
    b[0] = f2bf(lo.x); b[1] = f2bf(lo.y); b[2] = f2bf(lo.z); b[3] = f2bf(lo.w);
    b[4] = f2bf(hi.x); b[5] = f2bf(hi.y); b[6] = f2bf(hi.z); b[7] = f2bf(hi.w);
    return b;
}

// ---------------- node projection ----------------
// One wave per 16-node tile. Per block, w1 is converted once into a 32 KB LDS
// fragment table (coalesced reads), then waves read A-fragments via ds_read_b128.
// MFMA 16x16x32 bf16, A = weights, B = node features:
//   A[m][k]: lane provides row m=l&15 (dim within 16-block), k=8*(l>>4)+i
//   B[k][n]: lane provides col n=l&15 (node), same k
//   D: col=l&15 (node), row=4*(l>>4)+reg (dim within block)
// => lane owns node n0+(l&15); per dt it holds 4 consecutive dims -> 8 B stores.
__global__ __launch_bounds__(256) void node_proj_kernel(
    const float* __restrict__ x,    // [N][128]
    const float* __restrict__ w1,   // [64][256]
    const float* __restrict__ b1,   // [64]
    unsigned short* __restrict__ ytab, // [N][128] bf16 bits
    int N, int ntiles)
{
    __shared__ short wfrag[2048 * 8];   // 32 KB: [dt*4+kk][lane][8]

    // Cooperative w1 -> LDS fragment conversion. Thread v handles w1 flat
    // floats [v*64, v*64+64) — contiguous 256 B global reads per thread.
    {
        int v = threadIdx.x;
#pragma unroll
        for (int j = 0; j < 8; ++j) {
            int f = v * 64 + j * 8;          // flat index into w1 (64*256)
            int r = f >> 8;                  // w1 row (0..63)
            int k = f & 255;                 // col in [0,256)
            float4 lo = *(const float4*)(w1 + f);
            float4 hi = *(const float4*)(w1 + f + 4);
            int o, kk, g;
            if (k < IN_DIM) { o = r;          kk = k >> 5;             g = (k & 31) >> 3; }
            else            { o = r + HIDDEN; kk = (k - IN_DIM) >> 5;  g = ((k - IN_DIM) & 31) >> 3; }
            int dt = o >> 4, m = o & 15;
            int lane = g * 16 + m;
            *(bf16x8*)&wfrag[((dt * 4 + kk) * 64 + lane) * 8] = pack8(lo, hi);
        }
    }
    __syncthreads();

    int wave = (int)((blockIdx.x * blockDim.x + threadIdx.x) >> 6);
    if (wave >= ntiles) return;

    int lane = threadIdx.x & 63;
    int m = lane & 15;       // node offset within tile (B col, D col)
    int g = lane >> 4;       // k-group / D row group
    int n0 = wave * 16;

    int node = n0 + m;
    bool valid = node < N;
    int nclamp = valid ? node : N - 1;
    const float* xr = x + (size_t)nclamp * IN_DIM;

    bf16x8 xf[4];
#pragma unroll
    for (int kk = 0; kk < 4; ++kk) {
        int k0 = kk * 32 + g * 8;
        float4 lo = *(const float4*)(xr + k0);
        float4 hi = *(const float4*)(xr + k0 + 4);
        xf[kk] = pack8(lo, hi);
    }

    f32x4 acc[8] = {};
#pragma unroll
    for (int dt = 0; dt < 8; ++dt) {
#pragma unroll
        for (int kk = 0; kk < 4; ++kk) {
            bf16x8 wf = *(const bf16x8*)&wfrag[((dt * 4 + kk) * 64 + lane) * 8];
            acc[dt] = __builtin_amdgcn_mfma_f32_16x16x32_bf16(wf, xf[kk], acc[dt], 0, 0, 0);
        }
    }

    // epilogue: lane owns node, dims dt*16 + 4g + (0..3); fold b1 for dims<64
    if (valid) {
        unsigned short* yrow = ytab + (size_t)node * IN_DIM;
#pragma unroll
        for (int dt = 0; dt < 8; ++dt) {
            float4 b4;
            if (dt < 4) b4 = *(const float4*)(b1 + dt * 16 + g * 4);
            else        b4 = make_float4(0.f, 0.f, 0.f, 0.f);
            u16x4 s;
            s[0] = (unsigned short)f2bf(acc[dt][0] + b4.x);
            s[1] = (unsigned short)f2bf(acc[dt][1] + b4.y);
            s[2] = (unsigned short)f2bf(acc[dt][2] + b4.z);
            s[3] = (unsigned short)f2bf(acc[dt][3] + b4.w);
            *(u16x4*)(yrow + dt * 16 + g * 4) = s;
        }
    }
}

// ---------------- edge kernel: 8 lanes per edge, 4 edges per group ----------------
__device__ __forceinline__ float dimpair(unsigned u1, unsigned u2, float wlo, float whi, float acc) {
    float a0 = __uint_as_float(u1 << 16);
    float a1 = __uint_as_float(u1 & 0xffff0000u);
    float b0 = __uint_as_float(u2 << 16);
    float b1v = __uint_as_float(u2 & 0xffff0000u);
    float h0 = fmaxf(a0 + b0, 0.f);
    float h1 = fmaxf(a1 + b1v, 0.f);
    acc = fmaf(h0, wlo, acc);
    acc = fmaf(h1, whi, acc);
    return acc;
}

__device__ __forceinline__ float edge_dot(const uint4& ua, const uint4& ub,
                                          const float4& w2a, const float4& w2b) {
    float acc = 0.f;
    acc = dimpair(ua.x, ub.x, w2a.x, w2a.y, acc);
    acc = dimpair(ua.y, ub.y, w2a.z, w2a.w, acc);
    acc = dimpair(ua.z, ub.z, w2b.x, w2b.y, acc);
    acc = dimpair(ua.w, ub.w, w2b.z, w2b.w, acc);
    acc += __shfl_xor(acc, 1);
    acc += __shfl_xor(acc, 2);
    acc += __shfl_xor(acc, 4);
    return acc;
}

__device__ __forceinline__ float sigmoidf(float z) {
    return 1.f / (1.f + __expf(-z));
}

__global__ __launch_bounds__(256) void edge_kernel(
    const int* __restrict__ ei,                 // [2][E] int32
    const unsigned short* __restrict__ ytab,    // [N][128] bf16 bits
    const float* __restrict__ w2,               // [64]
    const float* __restrict__ b2,               // [1]
    float* __restrict__ out,                    // [E]
    int E)
{
    int t = (int)(blockIdx.x * 256 + threadIdx.x);
    int q = t >> 3;          // edge-quad id
    int sub = t & 7;
    int e0 = q * 4;
    if (e0 >= E) return;

    const char* yb = (const char*)ytab;
    float4 w2a = *((const float4*)w2 + sub * 2);
    float4 w2b = *((const float4*)w2 + sub * 2 + 1);
    int so = sub << 4;

    if (e0 + 4 <= E) {
        int4 rows = *(const int4*)(ei + e0);
        int4 cols = *(const int4*)(ei + E + e0);
        // issue all 8 gathers before any use (latency overlap)
        uint4 a0 = *(const uint4*)(yb + ((rows.x << 8) + so));
        uint4 a1 = *(const uint4*)(yb + ((rows.y << 8) + so));
        uint4 a2 = *(const uint4*)(yb + ((rows.z << 8) + so));
        uint4 a3 = *(const uint4*)(yb + ((rows.w << 8) + so));
        uint4 c0 = *(const uint4*)(yb + ((cols.x << 8) + 128 + so));
        uint4 c1 = *(const uint4*)(yb + ((cols.y << 8) + 128 + so));
        uint4 c2 = *(const uint4*)(yb + ((cols.z << 8) + 128 + so));
        uint4 c3 = *(const uint4*)(yb + ((cols.w << 8) + 128 + so));

        float z0 = edge_dot(a0, c0, w2a, w2b);
        float z1 = edge_dot(a1, c1, w2a, w2b);
        float z2 = edge_dot(a2, c2, w2a, w2b);
        float z3 = edge_dot(a3, c3, w2a, w2b);

        if (sub == 0) {
            float bb = b2[0];
            float4 s;
            s.x = sigmoidf(z0 + bb);
            s.y = sigmoidf(z1 + bb);
            s.z = sigmoidf(z2 + bb);
            s.w = sigmoidf(z3 + bb);
            *(float4*)(out + e0) = s;
        }
    } else {
        float bb = b2[0];
        for (int e = e0; e < E; ++e) {
            int row = ei[e];
            int col = ei[E + e];
            uint4 ua = *(const uint4*)(yb + ((row << 8) + so));
            uint4 ub = *(const uint4*)(yb + ((col << 8) + 128 + so));
            float z = edge_dot(ua, ub, w2a, w2b);
            if (sub == 0) out[e] = sigmoidf(z + bb);
        }
    }
}

extern "C" void kernel_launch(void* const* d_in, const int* in_sizes, int n_in,
                              void* d_out, int out_size, void* d_ws, size_t ws_size,
                              hipStream_t stream) {
    const float* x  = (const float*)d_in[0];
    const int*   ei = (const int*)d_in[1];
    const float* w1 = (const float*)d_in[2];
    const float* b1 = (const float*)d_in[3];
    const float* w2 = (const float*)d_in[4];
    const float* b2 = (const float*)d_in[5];
    float* out = (float*)d_out;

    int N = in_sizes[0] / IN_DIM;
    int E = in_sizes[1] / 2;

    unsigned short* ytab = (unsigned short*)d_ws;  // [N][128] bf16 = 12.8 MB

    int ntiles = (N + 15) / 16;
    int nblocks = (ntiles + 3) / 4;                 // 4 waves (tiles) per 256-thr block
    node_proj_kernel<<<nblocks, 256, 0, stream>>>(x, w1, b1, ytab, N, ntiles);

    long long quads = ((long long)E + 3) / 4;
    long long tthreads = quads * 8;
    int eblocks = (int)((tthreads + 255) / 256);
    edge_kernel<<<eblocks, 256, 0, stream>>>(ei, ytab, w2, b2, out, E);
}

// Round 4
// 65.033 us; speedup vs baseline: 1.3536x; 1.0049x over previous
//
#include <hip/hip_runtime.h>
#include <hip/hip_bf16.h>

// MaskNet edge scorer:
//   y1[n] = W1[:, :128] @ x[n] + b1   (64 dims, bf16, folded bias)
//   y2[n] = W1[:, 128:] @ x[n]        (64 dims, bf16)
//   s[e]  = sigmoid( w2 . relu(y1[row] + y2[col]) + b2 )
// ws layout: wtab (32 KB w1 fragment table, bf16) | ytab [N][128] bf16.

typedef __attribute__((ext_vector_type(8))) short bf16x8;
typedef __attribute__((ext_vector_type(4))) float f32x4;
typedef __attribute__((ext_vector_type(4))) unsigned short u16x4;

#define IN_DIM 128
#define HIDDEN 64

// native f32 -> bf16 (compiler emits v_cvt_pk_bf16_f32 for pairs, RNE)
__device__ __forceinline__ unsigned short bfbits(float f) {
    __hip_bfloat16 h = __float2bfloat16(f);
    return __builtin_bit_cast(unsigned short, h);
}

__device__ __forceinline__ bf16x8 pack8(const float4& lo, const float4& hi) {
    bf16x8 b;
    b[0] = (short)bfbits(lo.x); b[1] = (short)bfbits(lo.y);
    b[2] = (short)bfbits(lo.z); b[3] = (short)bfbits(lo.w);
    b[4] = (short)bfbits(hi.x); b[5] = (short)bfbits(hi.y);
    b[6] = (short)bfbits(hi.z); b[7] = (short)bfbits(hi.w);
    return b;
}

// ---------------- one-time w1 -> fragment table (32 KB) ----------------
// Layout: [dt*4+kk][lane][8] bf16, lane = g*16 + m.
//   dims o<64  -> w1 row o, cols [0,128)   (A-half, applies to x[row])
//   dims o>=64 -> w1 row o-64, cols [128,256) (B-half, applies to x[col])
__global__ __launch_bounds__(256) void convert_w1_kernel(
    const float* __restrict__ w1,         // [64][256]
    unsigned short* __restrict__ wtab)    // 16384 bf16
{
    int v = threadIdx.x;
#pragma unroll
    for (int j = 0; j < 8; ++j) {
        int f = v * 64 + j * 8;          // flat index into w1 (64*256)
        int r = f >> 8;                  // w1 row (0..63)
        int k = f & 255;                 // col in [0,256)
        float4 lo = *(const float4*)(w1 + f);
        float4 hi = *(const float4*)(w1 + f + 4);
        int o, kk, g;
        if (k < IN_DIM) { o = r;          kk = k >> 5;             g = (k & 31) >> 3; }
        else            { o = r + HIDDEN; kk = (k - IN_DIM) >> 5;  g = ((k - IN_DIM) & 31) >> 3; }
        int dt = o >> 4, m = o & 15;
        int lane = g * 16 + m;
        *(bf16x8*)&wtab[((dt * 4 + kk) * 64 + lane) * 8] = pack8(lo, hi);
    }
}

// ---------------- node projection (grid-stride, 512 blocks) ----------------
// One wave per 16-node tile iteration. wtab staged to LDS once per block.
// MFMA 16x16x32 bf16, A = weights, B = node features:
//   D: col=l&15 (node), row=4*(l>>4)+reg (dim within 16-block)
// => lane owns node n0+(l&15); per dt it holds 4 consecutive dims -> 8 B stores.
__global__ __launch_bounds__(256) void node_proj_kernel(
    const float* __restrict__ x,          // [N][128]
    const unsigned short* __restrict__ wtab,
    const float* __restrict__ b1,         // [64]
    unsigned short* __restrict__ ytab,    // [N][128] bf16 bits
    int N, int ntiles)
{
    __shared__ short wfrag[2048 * 8];   // 32 KB: [dt*4+kk][lane][8]

    {
        uint4* dst = (uint4*)wfrag;
        const uint4* src = (const uint4*)wtab;
        int v = threadIdx.x;
#pragma unroll
        for (int j = 0; j < 8; ++j) dst[v + j * 256] = src[v + j * 256];
    }
    __syncthreads();

    int lane = threadIdx.x & 63;
    int m = lane & 15;       // node offset within tile (B col, D col)
    int g = lane >> 4;       // k-group / D row group
    int gwave = (int)blockIdx.x * 4 + (threadIdx.x >> 6);
    int wstride = (int)gridDim.x * 4;

    for (int t = gwave; t < ntiles; t += wstride) {
        int n0 = t * 16;
        int node = n0 + m;
        bool valid = node < N;
        int nc = valid ? node : N - 1;
        const float* xr = x + (size_t)nc * IN_DIM;

        bf16x8 xf[4];
#pragma unroll
        for (int kk = 0; kk < 4; ++kk) {
            int k0 = kk * 32 + g * 8;
            float4 lo = *(const float4*)(xr + k0);
            float4 hi = *(const float4*)(xr + k0 + 4);
            xf[kk] = pack8(lo, hi);
        }

        f32x4 acc[8] = {};
#pragma unroll
        for (int dt = 0; dt < 8; ++dt) {
#pragma unroll
            for (int kk = 0; kk < 4; ++kk) {
                bf16x8 wf = *(const bf16x8*)&wfrag[((dt * 4 + kk) * 64 + lane) * 8];
                acc[dt] = __builtin_amdgcn_mfma_f32_16x16x32_bf16(wf, xf[kk], acc[dt], 0, 0, 0);
            }
        }

        if (valid) {
            unsigned short* yrow = ytab + (size_t)node * IN_DIM;
#pragma unroll
            for (int dt = 0; dt < 8; ++dt) {
                float4 b4;
                if (dt < 4) b4 = *(const float4*)(b1 + dt * 16 + g * 4);
                else        b4 = make_float4(0.f, 0.f, 0.f, 0.f);
                u16x4 s;
                s[0] = bfbits(acc[dt][0] + b4.x);
                s[1] = bfbits(acc[dt][1] + b4.y);
                s[2] = bfbits(acc[dt][2] + b4.z);
                s[3] = bfbits(acc[dt][3] + b4.w);
                *(u16x4*)(yrow + dt * 16 + g * 4) = s;
            }
        }
    }
}

// ---------------- edge kernel: 8 lanes per edge, 8 edges per group ----------------
__device__ __forceinline__ float dimpair(unsigned u1, unsigned u2, float wlo, float whi, float acc) {
    float a0 = __uint_as_float(u1 << 16);
    float a1 = __uint_as_float(u1 & 0xffff0000u);
    float b0 = __uint_as_float(u2 << 16);
    float b1v = __uint_as_float(u2 & 0xffff0000u);
    float h0 = fmaxf(a0 + b0, 0.f);
    float h1 = fmaxf(a1 + b1v, 0.f);
    acc = fmaf(h0, wlo, acc);
    acc = fmaf(h1, whi, acc);
    return acc;
}

__device__ __forceinline__ float edge_dot(const uint4& ua, const uint4& ub,
                                          const float4& w2a, const float4& w2b) {
    float acc = 0.f;
    acc = dimpair(ua.x, ub.x, w2a.x, w2a.y, acc);
    acc = dimpair(ua.y, ub.y, w2a.z, w2a.w, acc);
    acc = dimpair(ua.z, ub.z, w2b.x, w2b.y, acc);
    acc = dimpair(ua.w, ub.w, w2b.z, w2b.w, acc);
    acc += __shfl_xor(acc, 1);
    acc += __shfl_xor(acc, 2);
    acc += __shfl_xor(acc, 4);
    return acc;
}

__device__ __forceinline__ float sigmoidf(float z) {
    return 1.f / (1.f + __expf(-z));
}

__global__ __launch_bounds__(256) void edge_kernel(
    const int* __restrict__ ei,                 // [2][E] int32
    const unsigned short* __restrict__ ytab,    // [N][128] bf16 bits
    const float* __restrict__ w2,               // [64]
    const float* __restrict__ b2,               // [1]
    float* __restrict__ out,                    // [E]
    int E)
{
    int t = (int)(blockIdx.x * 256 + threadIdx.x);
    int q = t >> 3;          // edge-octet id
    int sub = t & 7;
    int e0 = q * 8;
    if (e0 >= E) return;

    const char* yb = (const char*)ytab;
    float4 w2a = *((const float4*)w2 + sub * 2);
    float4 w2b = *((const float4*)w2 + sub * 2 + 1);
    int so = sub << 4;

    if (e0 + 8 <= E) {
        int4 ra = *(const int4*)(ei + e0);
        int4 rb = *(const int4*)(ei + e0 + 4);
        int4 ca = *(const int4*)(ei + E + e0);
        int4 cb = *(const int4*)(ei + E + e0 + 4);
        // issue all 16 gathers before any use (latency overlap)
        uint4 a0 = *(const uint4*)(yb + ((ra.x << 8) + so));
        uint4 a1 = *(const uint4*)(yb + ((ra.y << 8) + so));
        uint4 a2 = *(const uint4*)(yb + ((ra.z << 8) + so));
        uint4 a3 = *(const uint4*)(yb + ((ra.w << 8) + so));
        uint4 a4 = *(const uint4*)(yb + ((rb.x << 8) + so));
        uint4 a5 = *(const uint4*)(yb + ((rb.y << 8) + so));
        uint4 a6 = *(const uint4*)(yb + ((rb.z << 8) + so));
        uint4 a7 = *(const uint4*)(yb + ((rb.w << 8) + so));
        uint4 c0 = *(const uint4*)(yb + ((ca.x << 8) + 128 + so));
        uint4 c1 = *(const uint4*)(yb + ((ca.y << 8) + 128 + so));
        uint4 c2 = *(const uint4*)(yb + ((ca.z << 8) + 128 + so));
        uint4 c3 = *(const uint4*)(yb + ((ca.w << 8) + 128 + so));
        uint4 c4 = *(const uint4*)(yb + ((cb.x << 8) + 128 + so));
        uint4 c5 = *(const uint4*)(yb + ((cb.y << 8) + 128 + so));
        uint4 c6 = *(const uint4*)(yb + ((cb.z << 8) + 128 + so));
        uint4 c7 = *(const uint4*)(yb + ((cb.w << 8) + 128 + so));

        float z0 = edge_dot(a0, c0, w2a, w2b);
        float z1 = edge_dot(a1, c1, w2a, w2b);
        float z2 = edge_dot(a2, c2, w2a, w2b);
        float z3 = edge_dot(a3, c3, w2a, w2b);
        float z4 = edge_dot(a4, c4, w2a, w2b);
        float z5 = edge_dot(a5, c5, w2a, w2b);
        float z6 = edge_dot(a6, c6, w2a, w2b);
        float z7 = edge_dot(a7, c7, w2a, w2b);

        if (sub == 0) {
            float bb = b2[0];
            float4 s0, s1;
            s0.x = sigmoidf(z0 + bb);
            s0.y = sigmoidf(z1 + bb);
            s0.z = sigmoidf(z2 + bb);
            s0.w = sigmoidf(z3 + bb);
            s1.x = sigmoidf(z4 + bb);
            s1.y = sigmoidf(z5 + bb);
            s1.z = sigmoidf(z6 + bb);
            s1.w = sigmoidf(z7 + bb);
            *(float4*)(out + e0) = s0;
            *(float4*)(out + e0 + 4) = s1;
        }
    } else {
        float bb = b2[0];
        for (int e = e0; e < E; ++e) {
            int row = ei[e];
            int col = ei[E + e];
            uint4 ua = *(const uint4*)(yb + ((row << 8) + so));
            uint4 ub = *(const uint4*)(yb + ((col << 8) + 128 + so));
            float z = edge_dot(ua, ub, w2a, w2b);
            if (sub == 0) out[e] = sigmoidf(z + bb);
        }
    }
}

extern "C" void kernel_launch(void* const* d_in, const int* in_sizes, int n_in,
                              void* d_out, int out_size, void* d_ws, size_t ws_size,
                              hipStream_t stream) {
    const float* x  = (const float*)d_in[0];
    const int*   ei = (const int*)d_in[1];
    const float* w1 = (const float*)d_in[2];
    const float* b1 = (const float*)d_in[3];
    const float* w2 = (const float*)d_in[4];
    const float* b2 = (const float*)d_in[5];
    float* out = (float*)d_out;

    int N = in_sizes[0] / IN_DIM;
    int E = in_sizes[1] / 2;

    unsigned short* wtab = (unsigned short*)d_ws;            // 32 KB fragment table
    unsigned short* ytab = (unsigned short*)d_ws + 16384;    // [N][128] bf16

    convert_w1_kernel<<<1, 256, 0, stream>>>(w1, wtab);

    int ntiles = (N + 15) / 16;
    node_proj_kernel<<<512, 256, 0, stream>>>(x, wtab, b1, ytab, N, ntiles);

    long long octs = ((long long)E + 7) / 8;
    long long tthreads = octs * 8;
    int eblocks = (int)((tthreads + 255) / 256);
    edge_kernel<<<eblocks, 256, 0, stream>>>(ei, ytab, w2, b2, out, E);
}